// Round 14
// baseline (553.348 us; speedup 1.0000x reference)
//
#include <hip/hip_runtime.h>
#include <math.h>

// Problem constants (reference: B,T,D,H = 64,512,256,256)
#define BB 64
#define TT 512
#define DD 256
#define HH 256
// out layout: sequence [B][T][2H] (fwd half | bwd half), then last_state [B][2H]

typedef float f32x8 __attribute__((ext_vector_type(8)));

// ---------------------------------------------------------------------------
// Kernel 1: x_proj = inputs @ W_ih + b -> both halves of sequence area.
// Unchanged (~143us; next target once scan is fixed).
// ---------------------------------------------------------------------------
__global__ __launch_bounds__(256) void xproj_kernel(
        const float* __restrict__ inp,
        const float* __restrict__ Wih,
        const float* __restrict__ bias,
        float* __restrict__ out) {
    __shared__ float wlds[64 * 256];   // 64 k-rows x 256 cols = 64 KiB
    const int tid = threadIdx.x;
    const int ty = tid >> 4;           // 0..15
    const int tx = tid & 15;           // 0..15
    const int m0 = blockIdx.x * 64;

    float acc[4][16];
    #pragma unroll
    for (int c = 0; c < 16; ++c) {
        float bv = bias[tx + 16 * c];
        #pragma unroll
        for (int r = 0; r < 4; ++r) acc[r][c] = bv;
    }

    for (int kt = 0; kt < 4; ++kt) {
        __syncthreads();
        const float4* wsrc = (const float4*)(Wih + kt * 64 * 256);
        float4* wdst = (float4*)wlds;
        #pragma unroll
        for (int i = 0; i < 16; ++i) wdst[tid + i * 256] = wsrc[tid + i * 256];
        __syncthreads();

        const float* arow = inp + (size_t)(m0 + ty * 4) * 256 + kt * 64;
        #pragma unroll 4
        for (int kk = 0; kk < 16; ++kk) {
            float4 a0 = *(const float4*)(arow + 0 * 256 + kk * 4);
            float4 a1 = *(const float4*)(arow + 1 * 256 + kk * 4);
            float4 a2 = *(const float4*)(arow + 2 * 256 + kk * 4);
            float4 a3 = *(const float4*)(arow + 3 * 256 + kk * 4);
            #pragma unroll
            for (int q = 0; q < 4; ++q) {
                const float* wrow = wlds + (kk * 4 + q) * 256;
                const float aq0 = (&a0.x)[q];
                const float aq1 = (&a1.x)[q];
                const float aq2 = (&a2.x)[q];
                const float aq3 = (&a3.x)[q];
                #pragma unroll
                for (int c = 0; c < 16; ++c) {
                    const float wv = wrow[tx + 16 * c];
                    acc[0][c] = fmaf(aq0, wv, acc[0][c]);
                    acc[1][c] = fmaf(aq1, wv, acc[1][c]);
                    acc[2][c] = fmaf(aq2, wv, acc[2][c]);
                    acc[3][c] = fmaf(aq3, wv, acc[3][c]);
                }
            }
        }
    }

    #pragma unroll
    for (int r = 0; r < 4; ++r) {
        const int m = m0 + ty * 4 + r;
        float* o = out + (size_t)m * 512;
        #pragma unroll
        for (int c = 0; c < 16; ++c) {
            const float v = acc[r][c];
            o[tx + 16 * c] = v;
            o[256 + tx + 16 * c] = v;
        }
    }
}

// ---------------------------------------------------------------------------
// Kernel 2: both scans. 128 wgs (64 fwd + 64 bwd), 1024 threads, 1 chain/wg.
// r5..r9 evidence: allocator refuses >=128-VGPR working sets (lands 88-92)
// regardless of pins. RESTRUCTURE so ~105 VGPRs SUFFICE:
//  - 1024-thr wg => 16 waves = 4/SIMD => hardware REQUIRES <=128 VGPR; the
//    compiler's natural budget now contains the working set (no fight).
//  - thread t: cg=t&63, kq=t>>6 (0..15): cols {cg+64c}, k in [16kq,16kq+16)
//    => 64 weights = 8 f32x8 = 64 VGPRs; 64 FMAs/step.
//  - 4 uniform b128 h-reads/thread (64/step/CU wave-instrs, same as r9).
//  - part[16][256] (17KB LDS); finish threads (t<256) sum 16 partials.
//  - light in-loop PINALL (8 ops, 64 regs) only to defeat load-sinking.
// ---------------------------------------------------------------------------
#define LOADW(n, c, q) { \
    const float* wp = Whh + (size_t)(kq * 16 + 8 * (q)) * 256 + cg + 64 * (c); \
    W##n[0] = wp[0 * 256]; W##n[1] = wp[1 * 256]; \
    W##n[2] = wp[2 * 256]; W##n[3] = wp[3 * 256]; \
    W##n[4] = wp[4 * 256]; W##n[5] = wp[5 * 256]; \
    W##n[6] = wp[6 * 256]; W##n[7] = wp[7 * 256]; }

#define PINALL asm volatile("" \
    : "+v"(W0), "+v"(W1), "+v"(W2), "+v"(W3), \
      "+v"(W4), "+v"(W5), "+v"(W6), "+v"(W7))

#define FMAQ(a, Wn, b) \
    a = fmaf(hv.x, Wn[(b) + 0], a); \
    a = fmaf(hv.y, Wn[(b) + 1], a); \
    a = fmaf(hv.z, Wn[(b) + 2], a); \
    a = fmaf(hv.w, Wn[(b) + 3], a);

#define STEP(i, Wa, Wb, Wc, Wd, b) { \
    const float4 hv = h4[i]; \
    FMAQ(acc0, Wa, b) FMAQ(acc1, Wb, b) FMAQ(acc2, Wc, b) FMAQ(acc3, Wd, b) }

__global__ __launch_bounds__(1024, 4)
void scan_kernel(
        const float* __restrict__ mask,
        const float* __restrict__ Whh,
        float* __restrict__ out) {
    __shared__ float hl[256];          // hidden state (single buffer)
    __shared__ float part[16][256];    // k-partials (16-way split)
    const int t = threadIdx.x;
    const int cg = t & 63;             // column group (owns cols cg+64c)
    const int kq = t >> 6;             // k-slice 0..15 (wave-uniform)
    const int wg = blockIdx.x;
    const int b = wg & 63;
    const bool fwd = (wg < 64);

    // 64 weights/thread in 8 f32x8: col c -> W(2c) k-rows 16kq..+7,
    // W(2c+1) k-rows 16kq+8..+15 (lane-consecutive cg -> coalesced loads).
    f32x8 W0, W1, W2, W3, W4, W5, W6, W7;
    LOADW(0,0,0) LOADW(1,0,1)
    LOADW(2,1,0) LOADW(3,1,1)
    LOADW(4,2,0) LOADW(5,2,1)
    LOADW(6,3,0) LOADW(7,3,1)

    if (t < 256) hl[t] = 0.0f;         // h0 = 0
    __syncthreads();

    float* seq = out + (size_t)b * TT * 512 + (fwd ? 0 : 256);
    float* last = out + (size_t)BB * TT * 512 + (size_t)b * 512 + (fwd ? 0 : 256);
    const float* mrow = mask + b * TT;

    int tcur = fwd ? 0 : TT - 1;
    float xp = 0.0f, mv = 0.0f;
    if (t < 256) {                     // finish threads (j = t)
        xp = seq[(size_t)tcur * 512 + t];
        mv = mrow[tcur];
    }

    const float4* h4 = (const float4*)(hl + kq * 16);

    #pragma unroll 1
    for (int tt = 0; tt < TT; ++tt) {
        PINALL;                        // keep weights live (defeat sinking)

        const int tn = fwd ? (tt + 1) : (TT - 2 - tt);
        float xp_n = 0.0f, mv_n = 0.0f;
        if (t < 256 && tt + 1 < TT) {  // prefetch lands under FMA phase
            xp_n = seq[(size_t)tn * 512 + t];
            mv_n = mrow[tn];
        }

        // 4 broadcast b128 reads feed 64 FMAs (16 per read)
        float acc0 = 0.f, acc1 = 0.f, acc2 = 0.f, acc3 = 0.f;
        STEP(0, W0, W2, W4, W6, 0)
        STEP(1, W0, W2, W4, W6, 4)
        STEP(2, W1, W3, W5, W7, 0)
        STEP(3, W1, W3, W5, W7, 4)

        part[kq][cg]       = acc0;
        part[kq][cg + 64]  = acc1;
        part[kq][cg + 128] = acc2;
        part[kq][cg + 192] = acc3;
        __syncthreads();               // partials visible

        if (t < 256) {
            const int j = t;
            const float s0 = (part[0][j]  + part[1][j])  + (part[2][j]  + part[3][j]);
            const float s1 = (part[4][j]  + part[5][j])  + (part[6][j]  + part[7][j]);
            const float s2 = (part[8][j]  + part[9][j])  + (part[10][j] + part[11][j]);
            const float s3 = (part[12][j] + part[13][j]) + (part[14][j] + part[15][j]);
            const float z = xp + ((s0 + s1) + (s2 + s3));
            // tanh(z) = 1 - 2/(e^{2z}+1); saturates correctly at +-inf
            const float e = __expf(2.0f * z);
            const float hn = 1.0f - 2.0f * __builtin_amdgcn_rcpf(e + 1.0f);

            seq[(size_t)tcur * 512 + j] = hn;          // sequence (unmasked)
            if (fwd) {
                if (tt == TT - 1) last[j] = hn;        // h_last_f
            } else {
                if (tt == 0) last[j] = hn;             // h_first_b
            }
            hl[j] = fwd ? hn : hn * mv;                // carry (bwd masked)
        }
        __syncthreads();               // h ready for next step
        tcur = tn;
        xp = xp_n;
        mv = mv_n;
    }
}

extern "C" void kernel_launch(void* const* d_in, const int* in_sizes, int n_in,
                              void* d_out, int out_size, void* d_ws, size_t ws_size,
                              hipStream_t stream) {
    const float* inp  = (const float*)d_in[0];   // (B,T,D)
    const float* mask = (const float*)d_in[1];   // (B,T)
    const float* Wih  = (const float*)d_in[2];   // (D,H)
    const float* Whh  = (const float*)d_in[3];   // (H,H)
    const float* bias = (const float*)d_in[4];   // (H,)
    float* out = (float*)d_out;

    xproj_kernel<<<512, 256, 0, stream>>>(inp, Wih, bias, out);
    scan_kernel<<<128, 1024, 0, stream>>>(mask, Whh, out);
}